// Round 5
// baseline (644.848 us; speedup 1.0000x reference)
//
#include <hip/hip_runtime.h>
#include <hip/hip_bf16.h>

// ---------- types ----------
typedef __bf16 bf16x8 __attribute__((ext_vector_type(8)));
typedef unsigned short u16x8 __attribute__((ext_vector_type(8)));
typedef unsigned short u16x4 __attribute__((ext_vector_type(4)));
typedef float f32x4 __attribute__((ext_vector_type(4)));
typedef float f32x16 __attribute__((ext_vector_type(16)));
typedef __attribute__((address_space(3))) unsigned short lds_u16;

__device__ __forceinline__ unsigned short f2bf(float f) {
  unsigned u = __float_as_uint(f);
  u += 0x7FFF + ((u >> 16) & 1);   // RNE to bf16
  return (unsigned short)(u >> 16);
}
__device__ __forceinline__ unsigned short f2bf_trunc(float f) {
  return (unsigned short)(__float_as_uint(f) >> 16);  // RTZ: fine for hi/lo splits
}
__device__ __forceinline__ float bf2f(unsigned short h) {
  return __uint_as_float(((unsigned)h) << 16);
}
__device__ __forceinline__ void gl_lds16(const void* g, lds_u16* l) {
  __builtin_amdgcn_global_load_lds((const __attribute__((address_space(1))) void*)g,
                                   (__attribute__((address_space(3))) void*)l, 16, 0, 0);
}

#define T_SEQ 2048
#define HIDDEN 4096
#define NQ_HEADS 32
#define NKV_HEADS 8
#define HEAD_DIM 128
#define QKV_N 6144
#define SCALE_QK 0.08838834764831845f   /* 1/sqrt(128) */
#define SCALE_H128 0.08838834764831845f /* 1/sqrt(128) */
#define SCALE_H32 0.17677669529663687f  /* 1/sqrt(32) */

// ---------- per-row int4 fake-quant, single-pass (row cached in registers) ----------
__global__ __launch_bounds__(256) void quant_rows(const float* __restrict__ X,
                                                  unsigned short* __restrict__ Q,
                                                  float* __restrict__ S, int C) {
  int row = blockIdx.x;
  int tid = threadIdx.x;
  const f32x4* x4 = (const f32x4*)(X + (size_t)row * C);
  f32x4 v[4];
  float amax = 0.f;
#pragma unroll
  for (int r = 0; r < 4; r++) {
    v[r] = x4[tid + r * 256];
#pragma unroll
    for (int e = 0; e < 4; e++) amax = fmaxf(amax, fabsf(v[r][e]));
  }
#pragma unroll
  for (int mm = 1; mm < 64; mm <<= 1) amax = fmaxf(amax, __shfl_xor(amax, mm, 64));
  __shared__ float red[4];
  if ((tid & 63) == 0) red[tid >> 6] = amax;
  __syncthreads();
  amax = fmaxf(fmaxf(red[0], red[1]), fmaxf(red[2], red[3]));
  float s = fmaxf(amax / 7.0f, 1e-8f);  // exact div to match reference
#pragma unroll
  for (int r = 0; r < 4; r++) {
    u16x4 q;
#pragma unroll
    for (int e = 0; e < 4; e++) {
      float wv = rintf(v[r][e] / s);    // RNE == jnp.round, exact div
      wv = fminf(fmaxf(wv, -8.f), 7.f);
      q[e] = f2bf(wv);                  // exact (small int)
    }
    *(u16x4*)&Q[(size_t)row * C + (tid + r * 256) * 4] = q;
  }
  if (tid == 0) S[row] = s;
}

// ---------- bf16(int-code) GEMM v2: A+B LDS double-buffer, 1 barrier per K-step ------
__global__ __launch_bounds__(256) void gemm_q4(const unsigned short* __restrict__ A,
                                               const unsigned short* __restrict__ B,
                                               const float* __restrict__ sa,
                                               const float* __restrict__ sb,
                                               const float* __restrict__ bias,
                                               float* __restrict__ C,
                                               int M, int N, int K, int hasBias) {
  __shared__ unsigned short As[2 * 128 * 32];
  __shared__ unsigned short Bs[2 * 128 * 32];
  lds_u16* As3 = (lds_u16*)As;
  lds_u16* Bs3 = (lds_u16*)Bs;
  const int tid = threadIdx.x;
  const int lane = tid & 63;
  const int w = tid >> 6;
  const int wm = w >> 1, wn = w & 1;
  const int quad = lane >> 4, l16 = lane & 15;
  const int m0 = blockIdx.y * 128, n0 = blockIdx.x * 128;

  const int u0 = w * 64 + lane;
  const int u1 = 256 + u0;
  const int row0 = u0 >> 2, col0 = (u0 & 3) ^ ((row0 >> 1) & 3);
  const int row1 = u1 >> 2, col1 = (u1 & 3) ^ ((row1 >> 1) & 3);
  const size_t ga0 = (size_t)(m0 + row0) * K + col0 * 8;
  const size_t ga1 = (size_t)(m0 + row1) * K + col1 * 8;
  const size_t gb0 = (size_t)(n0 + row0) * K + col0 * 8;
  const size_t gb1 = (size_t)(n0 + row1) * K + col1 * 8;
  const int d0 = w * 512;
  const int d1 = 2048 + w * 512;

  f32x4 acc[4][4] = {};
  const int nk = K >> 5;

  gl_lds16(&A[ga0], &As3[d0]);
  gl_lds16(&A[ga1], &As3[d1]);
  gl_lds16(&B[gb0], &Bs3[d0]);
  gl_lds16(&B[gb1], &Bs3[d1]);

#pragma unroll 1
  for (int kt = 0; kt < nk; kt++) {
    const int cur = kt & 1;
    asm volatile("s_waitcnt vmcnt(0)" ::: "memory");
    __builtin_amdgcn_s_barrier();
    if (kt + 1 < nk) {
      const int nb = (cur ^ 1) * 4096;             // OTHER buffer base, in shorts
      const size_t ko = (size_t)(kt + 1) * 32;
      gl_lds16(&A[ga0 + ko], &As3[nb + d0]);
      gl_lds16(&A[ga1 + ko], &As3[nb + d1]);
      gl_lds16(&B[gb0 + ko], &Bs3[nb + d0]);
      gl_lds16(&B[gb1 + ko], &Bs3[nb + d1]);
    }
    const unsigned short* Ac = As + cur * 4096;
    const unsigned short* Bc = Bs + cur * 4096;
    bf16x8 af[4], bfr[4];
#pragma unroll
    for (int i = 0; i < 4; i++) {
      int ra = wm * 64 + i * 16 + l16;
      int rb = wn * 64 + i * 16 + l16;
      af[i]  = *(const bf16x8*)&Ac[ra * 32 + (quad ^ ((ra >> 1) & 3)) * 8];
      bfr[i] = *(const bf16x8*)&Bc[rb * 32 + (quad ^ ((rb >> 1) & 3)) * 8];
    }
    __builtin_amdgcn_s_setprio(1);
#pragma unroll
    for (int i = 0; i < 4; i++)
#pragma unroll
      for (int j = 0; j < 4; j++)
        acc[i][j] = __builtin_amdgcn_mfma_f32_16x16x32_bf16(af[i], bfr[j], acc[i][j], 0, 0, 0);
    __builtin_amdgcn_s_setprio(0);
  }

#pragma unroll
  for (int i = 0; i < 4; i++) {
#pragma unroll
    for (int reg = 0; reg < 4; reg++) {
      int m = m0 + wm * 64 + i * 16 + quad * 4 + reg;
      float sm = sa[m];
#pragma unroll
      for (int j = 0; j < 4; j++) {
        int n = n0 + wn * 64 + j * 16 + l16;
        float v = acc[i][j][reg] * sm * sb[n];
        if (hasBias) v += bias[n];
        C[(size_t)m * N + n] = v;
      }
    }
  }
}

// ---------- RoPE + Hadamard-128 (q,k) and plain split (v); outputs hi/lo bf16 ----------
__global__ __launch_bounds__(256) void rope_had_kernel(const int* __restrict__ pos,
                                                       const float* __restrict__ qkv,
                                                       unsigned short* __restrict__ QH, unsigned short* __restrict__ QL,
                                                       unsigned short* __restrict__ KH, unsigned short* __restrict__ KL,
                                                       unsigned short* __restrict__ VH, unsigned short* __restrict__ VL) {
  const int w = threadIdx.x >> 6, lane = threadIdx.x & 63;
  const int vec = blockIdx.x * 4 + w;   // wave-uniform branch below
  int t, h; const float* src; unsigned short *dH, *dL; size_t o; bool doRot;
  if (vec < T_SEQ * NQ_HEADS) {
    t = vec >> 5; h = vec & 31;
    src = qkv + (size_t)t * QKV_N + h * HEAD_DIM;
    dH = QH; dL = QL; o = ((size_t)t * NQ_HEADS + h) * HEAD_DIM; doRot = true;
  } else if (vec < T_SEQ * (NQ_HEADS + NKV_HEADS)) {
    int i2 = vec - T_SEQ * NQ_HEADS; t = i2 >> 3; h = i2 & 7;
    src = qkv + (size_t)t * QKV_N + 4096 + h * HEAD_DIM;
    dH = KH; dL = KL; o = ((size_t)t * NKV_HEADS + h) * HEAD_DIM; doRot = true;
  } else {
    int i2 = vec - T_SEQ * (NQ_HEADS + NKV_HEADS); t = i2 >> 3; h = i2 & 7;
    src = qkv + (size_t)t * QKV_N + 5120 + h * HEAD_DIM;
    dH = VH; dL = VL; o = ((size_t)t * NKV_HEADS + h) * HEAD_DIM; doRot = false;
  }
  float a = src[lane], b = src[lane + 64];
  if (doRot) {
    float p = (float)pos[t];
    float fr = exp2f(-0.207620506f * (float)lane);   // 10000^-(lane/64)
    float ang = p * fr;
    float cs = cosf(ang), sn = sinf(ang);
    float na = a * cs - b * sn;
    float nb = b * cs + a * sn;
    a = na + nb; b = na - nb;
#pragma unroll
    for (int mm = 1; mm <= 32; mm <<= 1) {
      float pa = __shfl_xor(a, mm, 64);
      float pb = __shfl_xor(b, mm, 64);
      bool hi = (lane & mm) != 0;
      a = hi ? (pa - a) : (a + pa);
      b = hi ? (pb - b) : (b + pb);
    }
    a *= SCALE_H128; b *= SCALE_H128;
  }
  unsigned short ah = f2bf(a), bh = f2bf(b);
  dH[o + lane] = ah;       dH[o + lane + 64] = bh;
  dL[o + lane] = f2bf(a - bf2f(ah));
  dL[o + lane + 64] = f2bf(b - bf2f(bh));
}

// ---------- V transpose: [t][hk][128] hi/lo -> V^T [hk][128][2048] hi/lo ----------
__global__ __launch_bounds__(256) void vtrans_kernel(const unsigned short* __restrict__ Vh,
                                                     const unsigned short* __restrict__ Vl,
                                                     unsigned short* __restrict__ VtH,
                                                     unsigned short* __restrict__ VtL) {
  __shared__ unsigned short sm[17408];  // 2 x 64x136
  unsigned short* SH = sm;
  unsigned short* SL = sm + 8704;
  const int tid = threadIdx.x;
  const int t0 = blockIdx.x * 64, h = blockIdx.y;
#pragma unroll
  for (int r = 0; r < 4; r++) {
    int G = tid + r * 256;             // 1024 granules of 8 shorts
    int row = G >> 4, g = G & 15;
    size_t src = ((size_t)(t0 + row) * NKV_HEADS + h) * HEAD_DIM + g * 8;
    *(u16x8*)&SH[row * 136 + g * 8] = *(const u16x8*)&Vh[src];
    *(u16x8*)&SL[row * 136 + g * 8] = *(const u16x8*)&Vl[src];
  }
  __syncthreads();
#pragma unroll
  for (int r = 0; r < 4; r++) {
    int G = tid + r * 256;
    int d = G >> 3, gt = G & 7;
    u16x8 a, b;
#pragma unroll
    for (int e = 0; e < 8; e++) {
      a[e] = SH[(gt * 8 + e) * 136 + d];
      b[e] = SL[(gt * 8 + e) * 136 + d];
    }
    size_t dst = ((size_t)h * HEAD_DIM + d) * T_SEQ + t0 + gt * 8;
    *(u16x8*)&VtH[dst] = a;
    *(u16x8*)&VtL[dst] = b;
  }
}

// ---------- flash attention v7: 32x32x16 MFMA, P in registers, 2 blocks/CU -----------
// 256 blocks x 256 threads (4 waves, 2 blocks/CU). Block = 2 q-heads x 64 q-rows
// (wave = 1 head x 32 q-rows via 32x32 MFMA). Same K/V staging + XOR swizzles +
// 1-barrier aged-prefetch pipeline + qt-pair balancing as v6, but: 2x FLOP per LDS
// byte (16B fragment feeds 32K FLOP), and P stays in registers (cross-half exchange
// via shfl_xor(32)) -> LDS traffic per unit work halved; P LDS buffer eliminated
// (64 KB/block -> 2 blocks/CU).
// Layouts (HW-verified m74/m101): C/D col=lane&31, row=(reg&3)+8*(reg>>2)+4*(lane>>5);
// A: m=lane&31, k=8*(lane>>5)+i; B: n=lane&31, k=8*(lane>>5)+i.
__global__ __launch_bounds__(256, 2) void attn_kernel(const unsigned short* __restrict__ Qh, const unsigned short* __restrict__ Ql,
                                                      const unsigned short* __restrict__ Kh, const unsigned short* __restrict__ Kl,
                                                      const unsigned short* __restrict__ VtH, const unsigned short* __restrict__ VtL,
                                                      float* __restrict__ O) {
  __shared__ unsigned short smem[32768];   // 65536 B
  // K buf c: [c*8192, +4096) = KH, +4096 = KL        (phys g16 = log ^ (key&7))
  // V buf c: 16384 + c*8192: VH, +4096 = VL          (phys g4  = log ^ ((d>>1)&3))
  const int tid = threadIdx.x, lane = tid & 63, w = tid >> 6;
  const int l32 = lane & 31, hh = lane >> 5;   // half-select within wave

  const int b = blockIdx.x;
  const int hk = b & 7;                  // round-robin dispatch: XCD x owns kv-head x
  const int idx = b >> 3;                // 0..31
  const int hp = idx & 1;                // head pair within kv-group
  const int u = idx >> 1;                // 0..15 ; phases run qt=u then qt=31-u
  const int head = hk * 4 + hp * 2 + (w >> 1);
  const int qh = w & 1;                  // q 32-row half within the 64-row tile

  // staging granule geometry (256 threads, 2 granules per matrix-half per thread)
  const int kr0 = tid >> 4,         kg0 = (tid & 15) ^ (kr0 & 7);
  const int kr1 = 16 + (tid >> 4),  kg1 = (tid & 15) ^ (kr1 & 7);
  const size_t ko0 = ((size_t)kr0 * NKV_HEADS + hk) * HEAD_DIM + kg0 * 8;
  const size_t ko1 = ((size_t)kr1 * NKV_HEADS + hk) * HEAD_DIM + kg1 * 8;
  const int vd0 = tid >> 2,         vg0 = (tid & 3) ^ ((vd0 >> 1) & 3);
  const int vd1 = 64 + (tid >> 2),  vg1 = (tid & 3) ^ ((vd1 >> 1) & 3);
  const size_t vo0 = ((size_t)hk * HEAD_DIM + vd0) * T_SEQ + vg0 * 8;
  const size_t vo1 = ((size_t)hk * HEAD_DIM + vd1) * T_SEQ + vg1 * 8;
  const size_t kTile = (size_t)32 * NKV_HEADS * HEAD_DIM;

#pragma unroll 1
  for (int ph = 0; ph < 2; ph++) {
    const int qt = ph ? (31 - u) : u;
    const int q0 = qt * 64;
    const int qcol = q0 + qh * 32 + l32;     // this lane's q (softmax/O column)
    const int wqmax = q0 + qh * 32 + 31;
    const int nkt = 2 * qt + 2;

    // Q fragments (B-operand of S^T): n = q = l32, k = s*16 + 8*hh + i (contiguous 8)
    bf16x8 qbh[8], qbl[8];
#pragma unroll
    for (int s = 0; s < 8; s++) {
      size_t g = ((size_t)qcol * NQ_HEADS + head) * HEAD_DIM + s * 16 + 8 * hh;
      qbh[s] = *(const bf16x8*)&Qh[g];
      qbl[s] = *(const bf16x8*)&Ql[g];
    }
    f32x16 oacc[4] = {};
    float mrow = -__builtin_inff();
    float lrow = 0.f;

    if (ph == 0) {
      // cold start: stage tile 0 into buf 0 (phase-1 tile 0 staged by phase-0's last)
      gl_lds16(&Kh[ko0],  (lds_u16*)&smem[w * 512]);
      gl_lds16(&Kh[ko1],  (lds_u16*)&smem[2048 + w * 512]);
      gl_lds16(&Kl[ko0],  (lds_u16*)&smem[4096 + w * 512]);
      gl_lds16(&Kl[ko1],  (lds_u16*)&smem[6144 + w * 512]);
      gl_lds16(&VtH[vo0], (lds_u16*)&smem[16384 + w * 512]);
      gl_lds16(&VtH[vo1], (lds_u16*)&smem[16384 + 2048 + w * 512]);
      gl_lds16(&VtL[vo0], (lds_u16*)&smem[16384 + 4096 + w * 512]);
      gl_lds16(&VtL[vo1], (lds_u16*)&smem[16384 + 6144 + w * 512]);
    }

#pragma unroll 1
    for (int kt = 0; kt < nkt; kt++) {
      const int cur = kt & 1;
      const unsigned short* KcH = smem + cur * 8192;
      const unsigned short* KcL = KcH + 4096;
      const unsigned short* VcH = smem + 16384 + cur * 8192;
      const unsigned short* VcL = VcH + 4096;
      // ---- the one barrier: own prefetch (aged a full iteration) drained, then
      // rendezvous -> tile kt resident in LDS for all waves; prev buffer free ----
      asm volatile("s_waitcnt vmcnt(0)" ::: "memory");
      __builtin_amdgcn_s_barrier();
      {
        int tn = -1;
        if (kt + 1 < nkt) tn = kt + 1;
        else if (ph == 0) tn = 0;            // phase-1 tile 0 -> buf 0 (nkt even)
        if (tn >= 0) {
          const int nb = tn & 1;
          unsigned short* KB = smem + nb * 8192;
          unsigned short* VB = smem + 16384 + nb * 8192;
          size_t kOff = (size_t)tn * kTile;
          size_t vOff = (size_t)tn * 32;
          gl_lds16(&Kh[kOff + ko0],  (lds_u16*)&KB[w * 512]);
          gl_lds16(&Kh[kOff + ko1],  (lds_u16*)&KB[2048 + w * 512]);
          gl_lds16(&Kl[kOff + ko0],  (lds_u16*)&KB[4096 + w * 512]);
          gl_lds16(&Kl[kOff + ko1],  (lds_u16*)&KB[6144 + w * 512]);
          gl_lds16(&VtH[vOff + vo0], (lds_u16*)&VB[w * 512]);
          gl_lds16(&VtH[vOff + vo1], (lds_u16*)&VB[2048 + w * 512]);
          gl_lds16(&VtL[vOff + vo0], (lds_u16*)&VB[4096 + w * 512]);
          gl_lds16(&VtL[vOff + vo1], (lds_u16*)&VB[6144 + w * 512]);
        }
      }
      const bool active = (kt * 32 <= wqmax);   // wave-uniform
      if (!active) continue;

      // S^T = K . Q^T  (A=K: m=key=l32, k=s*16+8*hh+i; D col=q=l32, row=key)
      f32x16 sc = {};
      __builtin_amdgcn_s_setprio(1);
#pragma unroll
      for (int s = 0; s < 8; s++) {
        int phys = (s * 2 + hh) ^ (l32 & 7);
        bf16x8 kah = *(const bf16x8*)&KcH[l32 * 128 + phys * 8];
        bf16x8 kal = *(const bf16x8*)&KcL[l32 * 128 + phys * 8];
        sc = __builtin_amdgcn_mfma_f32_32x32x16_bf16(kah, qbh[s], sc, 0, 0, 0);
        sc = __builtin_amdgcn_mfma_f32_32x32x16_bf16(kah, qbl[s], sc, 0, 0, 0);
        sc = __builtin_amdgcn_mfma_f32_32x32x16_bf16(kal, qbh[s], sc, 0, 0, 0);
      }
      __builtin_amdgcn_s_setprio(0);

      // causal mask (diagonal tiles only; wave-uniform test). key(reg) layout above.
      if (kt * 32 + 31 > q0 + qh * 32) {
#pragma unroll
        for (int r = 0; r < 16; r++) {
          int kg = kt * 32 + (r & 3) + 8 * (r >> 2) + 4 * hh;
          if (kg > qcol) sc[r] = -__builtin_inff();
        }
      }

      // online softmax in RAW score domain; lane owns one q col (16 keys; partner
      // half holds the other 16 -> one shfl_xor(32) completes the reduce)
      float tmax = sc[0];
#pragma unroll
      for (int r = 1; r < 16; r++) tmax = fmaxf(tmax, sc[r]);
      tmax = fmaxf(tmax, __shfl_xor(tmax, 32, 64));
      // defer-max (T13): skip O/l rescale while growth <= 4 in scaled domain
      if (!__all(tmax <= mrow + 45.2548f)) {
        float mnew = fmaxf(mrow, tmax);
        float alpha = __expf((mrow - mnew) * SCALE_QK);
        mrow = mnew;
        lrow *= alpha;
#pragma unroll
        for (int db = 0; db < 4; db++) oacc[db] *= alpha;
      }
      float negm = -mrow * SCALE_QK;
      float rs = 0.f;
#pragma unroll
      for (int r = 0; r < 16; r++) {
        float p = __expf(__builtin_fmaf(sc[r], SCALE_QK, negm));
        sc[r] = p;
        rs += p;
      }
      rs += __shfl_xor(rs, 32, 64);
      lrow += rs;

      // P -> bf16 hi/lo packs, in-register cross-half exchange (no LDS).
      // pair j holds keys: j0:(0,1) j1:(2,3) j2:(8,9) j3:(10,11) j4:(16,17)
      // j5:(18,19) j6:(24,25) j7:(26,27), each +4*hh.
      unsigned hi[8], lo[8];
#pragma unroll
      for (int j = 0; j < 8; j++) {
        float pa = sc[2 * j], pb = sc[2 * j + 1];
        unsigned short ha = f2bf_trunc(pa);
        unsigned short hb = f2bf_trunc(pb);
        unsigned short la = f2bf_trunc(pa - bf2f(ha));
        unsigned short lb = f2bf_trunc(pb - bf2f(hb));
        hi[j] = (unsigned)ha | ((unsigned)hb << 16);
        lo[j] = (unsigned)la | ((unsigned)lb << 16);
      }
      unsigned xh[8], xl[8];
#pragma unroll
      for (int j = 0; j < 8; j++) {
        xh[j] = __shfl_xor(hi[j], 32, 64);
        xl[j] = __shfl_xor(lo[j], 32, 64);
      }
      // B-frag step s needs keys s*16 + 8*hh .. +7  (n = q = l32 matches C col)
      union U4 { unsigned u[4]; bf16x8 v; };
      U4 fh[2], fl[2];
#pragma unroll
      for (int s = 0; s < 2; s++) {
        int b0 = s * 4;
        fh[s].u[0] = hh ? xh[b0 + 2] : hi[b0 + 0];
        fh[s].u[1] = hh ? xh[b0 + 3] : hi[b0 + 1];
        fh[s].u[2] = hh ? hi[b0 + 2] : xh[b0 + 0];
        fh[s].u[3] = hh ? hi[b0 + 3] : xh[b0 + 1];
        fl[s].u[0] = hh ? xl[b0 + 2] : lo[b0 + 0];
        fl[s].u[1] = hh ? xl[b0 + 3] : lo[b0 + 1];
        fl[s].u[2] = hh ? lo[b0 + 2] : xl[b0 + 0];
        fl[s].u[3] = hh ? lo[b0 + 3] : xl[b0 + 1];
      }

      // O^T += V^T . P  (A=V^T: m=d=db*32+l32, k=keys s*16+8*hh+i; D col=q, row=d)
      __builtin_amdgcn_s_setprio(1);
#pragma unroll
      for (int db = 0; db < 4; db++) {
        int d = db * 32 + l32;
#pragma unroll
        for (int s = 0; s < 2; s++) {
          int phys = (s * 2 + hh) ^ ((d >> 1) & 3);
          bf16x8 vah = *(const bf16x8*)&VcH[d * 32 + phys * 8];
          bf16x8 val = *(const bf16x8*)&VcL[d * 32 + phys * 8];
          oacc[db] = __builtin_amdgcn_mfma_f32_32x32x16_bf16(vah, fh[s].v, oacc[db], 0, 0, 0);
          oacc[db] = __builtin_amdgcn_mfma_f32_32x32x16_bf16(vah, fl[s].v, oacc[db], 0, 0, 0);
          oacc[db] = __builtin_amdgcn_mfma_f32_32x32x16_bf16(val, fh[s].v, oacc[db], 0, 0, 0);
        }
      }
      __builtin_amdgcn_s_setprio(0);
    }

    // phase epilogue: per-lane normalize; f32x4 stores.
    // reg 4g+j of oacc[db] -> d = db*32 + 8*g + 4*hh + j (j=0..3 contiguous)
    float inv = 1.0f / lrow;
#pragma unroll
    for (int db = 0; db < 4; db++) {
#pragma unroll
      for (int g = 0; g < 4; g++) {
        f32x4 o;
        o[0] = oacc[db][4 * g + 0] * inv;
        o[1] = oacc[db][4 * g + 1] * inv;
        o[2] = oacc[db][4 * g + 2] * inv;
        o[3] = oacc[db][4 * g + 3] * inv;
        *(f32x4*)&O[((size_t)qcol * NQ_HEADS + head) * HEAD_DIM + db * 32 + 8 * g + 4 * hh] = o;
      }
    }
  }
}

// ---------- head-Hadamard (32) + per-token int4 fake-quant ----------
__global__ __launch_bounds__(128) void headhad_quant(const float* __restrict__ attn,
                                                     unsigned short* __restrict__ Aq,
                                                     float* __restrict__ Sa) {
  const int t = blockIdx.x, d = threadIdx.x; // 128 threads, one d-column each
  float x[32];
#pragma unroll
  for (int h = 0; h < 32; h++) x[h] = attn[(size_t)t * 4096 + h * 128 + d];
#pragma unroll
  for (int s = 1; s < 32; s <<= 1) {
#pragma unroll
    for (int i = 0; i < 32; i++) {
      if (!(i & s)) {
        float u = x[i], v = x[i | s];
        x[i] = u + v; x[i | s] = u - v;
      }
    }
  }
  float amax = 0.f;
#pragma unroll
  for (int h = 0; h < 32; h++) { x[h] *= SCALE_H32; amax = fmaxf(amax, fabsf(x[h])); }
#pragma unroll
  for (int mm = 1; mm < 64; mm <<= 1) amax = fmaxf(amax, __shfl_xor(amax, mm, 64));
  __shared__ float red[2];
  if ((threadIdx.x & 63) == 0) red[threadIdx.x >> 6] = amax;
  __syncthreads();
  amax = fmaxf(red[0], red[1]);
  float s = fmaxf(amax / 7.0f, 1e-8f);
#pragma unroll
  for (int h = 0; h < 32; h++) {
    float q = rintf(x[h] / s);
    q = fminf(fmaxf(q, -8.f), 7.f);
    Aq[(size_t)t * 4096 + h * 128 + d] = f2bf(q);
  }
  if (threadIdx.x == 0) Sa[t] = s;
}

// ---------- launch ----------
extern "C" void kernel_launch(void* const* d_in, const int* in_sizes, int n_in,
                              void* d_out, int out_size, void* d_ws, size_t ws_size,
                              hipStream_t stream) {
  const int*   positions = (const int*)d_in[0];
  const float* hidden    = (const float*)d_in[1];
  const float* qkv_w     = (const float*)d_in[2];
  const float* qkv_b     = (const float*)d_in[3];
  const float* o_w       = (const float*)d_in[4];
  float* out = (float*)d_out;
  char* ws = (char*)d_ws;

  // region map (total ~160.1 MB)
  unsigned short* wq   = (unsigned short*)(ws + 0);          // 6144x4096 bf16 ; later owq 4096x4096
  unsigned short* xq   = (unsigned short*)(ws + 50331648);   // 2048x4096 bf16 ; later vth/vtl then aq
  float*          qkv  = (float*)(ws + 67108864);            // 2048x6144 f32 ; later attn f32
  unsigned short* qh   = (unsigned short*)(ws + 117440512);  // 2048x32x128
  unsigned short* ql   = (unsigned short*)(ws + 134217728);
  unsigned short* kh   = (unsigned short*)(ws + 150994944);  // 2048x8x128
  unsigned short* kl   = (unsigned short*)(ws + 155189248);
  unsigned short* vh   = (unsigned short*)(ws + 159383552);
  unsigned short* vl   = (unsigned short*)(ws + 163577856);
  float* s_x  = (float*)(ws + 167772160);
  float* s_w  = (float*)(ws + 167780352);
  float* s_a  = (float*)(ws + 167804928);
  float* s_ow = (float*)(ws + 167813120);
  unsigned short* owq  = wq;                                 // reuse R0 after GEMM1
  unsigned short* aq   = xq;                                 // reuse R1 after attn
  unsigned short* vth  = (unsigned short*)(ws + 50331648);   // inside R1 (xq dead after GEMM1)
  unsigned short* vtl  = (unsigned short*)(ws + 54525952);
  float* attnbuf       = qkv;                                // reuse R2 after rope

  // 1. quantize activations + qkv weights (single-pass)
  quant_rows<<<T_SEQ, 256, 0, stream>>>(hidden, xq, s_x, HIDDEN);
  quant_rows<<<QKV_N, 256, 0, stream>>>(qkv_w, wq, s_w, HIDDEN);
  // 2. QKV GEMM (exact int4 dot in bf16 MFMA), pipelined staging
  gemm_q4<<<dim3(QKV_N / 128, T_SEQ / 128), 256, 0, stream>>>(xq, wq, s_x, s_w, qkv_b,
                                                              qkv, T_SEQ, QKV_N, HIDDEN, 1);
  // 3. RoPE + Hadamard-128, hi/lo split outputs
  rope_had_kernel<<<(T_SEQ * 48) / 4, 256, 0, stream>>>(positions, qkv, qh, ql, kh, kl, vh, vl);
  // 3b. V transpose into [hk][d][t] (R1 is free now)
  vtrans_kernel<<<dim3(T_SEQ / 64, NKV_HEADS), 256, 0, stream>>>(vh, vl, vth, vtl);
  // 4. quantize o_w (into reused R0)
  quant_rows<<<HIDDEN, 256, 0, stream>>>(o_w, owq, s_ow, HIDDEN);
  // 5. attention v7: 32x32 MFMA, in-reg P, 2 blocks/CU; writes into reused R2
  attn_kernel<<<dim3(256), 256, 0, stream>>>(qh, ql, kh, kl, vth, vtl, attnbuf);
  // 6. head-Hadamard + per-token fake-quant (into reused R1; vth/vtl dead)
  headhad_quant<<<T_SEQ, 128, 0, stream>>>(attnbuf, aq, s_a);
  // 7. O-proj GEMM, pipelined staging
  gemm_q4<<<dim3(HIDDEN / 128, T_SEQ / 128), 256, 0, stream>>>(aq, owq, s_a, s_ow, nullptr,
                                                               out, T_SEQ, HIDDEN, HIDDEN, 0);
}

// Round 6
// 604.226 us; speedup vs baseline: 1.0672x; 1.0672x over previous
//
#include <hip/hip_runtime.h>
#include <hip/hip_bf16.h>

// ---------- types ----------
typedef __bf16 bf16x8 __attribute__((ext_vector_type(8)));
typedef unsigned short u16x8 __attribute__((ext_vector_type(8)));
typedef unsigned short u16x4 __attribute__((ext_vector_type(4)));
typedef float f32x4 __attribute__((ext_vector_type(4)));
typedef float f32x16 __attribute__((ext_vector_type(16)));
typedef __attribute__((address_space(3))) unsigned short lds_u16;

__device__ __forceinline__ unsigned short f2bf(float f) {
  unsigned u = __float_as_uint(f);
  u += 0x7FFF + ((u >> 16) & 1);   // RNE to bf16
  return (unsigned short)(u >> 16);
}
__device__ __forceinline__ unsigned short f2bf_trunc(float f) {
  return (unsigned short)(__float_as_uint(f) >> 16);  // RTZ: fine for hi/lo splits
}
__device__ __forceinline__ float bf2f(unsigned short h) {
  return __uint_as_float(((unsigned)h) << 16);
}
__device__ __forceinline__ void gl_lds16(const void* g, lds_u16* l) {
  __builtin_amdgcn_global_load_lds((const __attribute__((address_space(1))) void*)g,
                                   (__attribute__((address_space(3))) void*)l, 16, 0, 0);
}

#define T_SEQ 2048
#define HIDDEN 4096
#define NQ_HEADS 32
#define NKV_HEADS 8
#define HEAD_DIM 128
#define QKV_N 6144
#define SCALE_QK 0.08838834764831845f   /* 1/sqrt(128) */
#define SCALE_H128 0.08838834764831845f /* 1/sqrt(128) */
#define SCALE_H32 0.17677669529663687f  /* 1/sqrt(32) */

// ---------- per-row int4 fake-quant, single-pass (row cached in registers) ----------
__global__ __launch_bounds__(256) void quant_rows(const float* __restrict__ X,
                                                  unsigned short* __restrict__ Q,
                                                  float* __restrict__ S, int C) {
  int row = blockIdx.x;
  int tid = threadIdx.x;
  const f32x4* x4 = (const f32x4*)(X + (size_t)row * C);
  f32x4 v[4];
  float amax = 0.f;
#pragma unroll
  for (int r = 0; r < 4; r++) {
    v[r] = x4[tid + r * 256];
#pragma unroll
    for (int e = 0; e < 4; e++) amax = fmaxf(amax, fabsf(v[r][e]));
  }
#pragma unroll
  for (int mm = 1; mm < 64; mm <<= 1) amax = fmaxf(amax, __shfl_xor(amax, mm, 64));
  __shared__ float red[4];
  if ((tid & 63) == 0) red[tid >> 6] = amax;
  __syncthreads();
  amax = fmaxf(fmaxf(red[0], red[1]), fmaxf(red[2], red[3]));
  float s = fmaxf(amax / 7.0f, 1e-8f);  // exact div to match reference
#pragma unroll
  for (int r = 0; r < 4; r++) {
    u16x4 q;
#pragma unroll
    for (int e = 0; e < 4; e++) {
      float wv = rintf(v[r][e] / s);    // RNE == jnp.round, exact div
      wv = fminf(fmaxf(wv, -8.f), 7.f);
      q[e] = f2bf(wv);                  // exact (small int)
    }
    *(u16x4*)&Q[(size_t)row * C + (tid + r * 256) * 4] = q;
  }
  if (tid == 0) S[row] = s;
}

// ---------- bf16(int-code) GEMM v2: A+B LDS double-buffer, 1 barrier per K-step ------
__global__ __launch_bounds__(256) void gemm_q4(const unsigned short* __restrict__ A,
                                               const unsigned short* __restrict__ B,
                                               const float* __restrict__ sa,
                                               const float* __restrict__ sb,
                                               const float* __restrict__ bias,
                                               float* __restrict__ C,
                                               int M, int N, int K, int hasBias) {
  __shared__ unsigned short As[2 * 128 * 32];
  __shared__ unsigned short Bs[2 * 128 * 32];
  lds_u16* As3 = (lds_u16*)As;
  lds_u16* Bs3 = (lds_u16*)Bs;
  const int tid = threadIdx.x;
  const int lane = tid & 63;
  const int w = tid >> 6;
  const int wm = w >> 1, wn = w & 1;
  const int quad = lane >> 4, l16 = lane & 15;
  const int m0 = blockIdx.y * 128, n0 = blockIdx.x * 128;

  const int u0 = w * 64 + lane;
  const int u1 = 256 + u0;
  const int row0 = u0 >> 2, col0 = (u0 & 3) ^ ((row0 >> 1) & 3);
  const int row1 = u1 >> 2, col1 = (u1 & 3) ^ ((row1 >> 1) & 3);
  const size_t ga0 = (size_t)(m0 + row0) * K + col0 * 8;
  const size_t ga1 = (size_t)(m0 + row1) * K + col1 * 8;
  const size_t gb0 = (size_t)(n0 + row0) * K + col0 * 8;
  const size_t gb1 = (size_t)(n0 + row1) * K + col1 * 8;
  const int d0 = w * 512;
  const int d1 = 2048 + w * 512;

  f32x4 acc[4][4] = {};
  const int nk = K >> 5;

  gl_lds16(&A[ga0], &As3[d0]);
  gl_lds16(&A[ga1], &As3[d1]);
  gl_lds16(&B[gb0], &Bs3[d0]);
  gl_lds16(&B[gb1], &Bs3[d1]);

#pragma unroll 1
  for (int kt = 0; kt < nk; kt++) {
    const int cur = kt & 1;
    asm volatile("s_waitcnt vmcnt(0)" ::: "memory");
    __builtin_amdgcn_s_barrier();
    if (kt + 1 < nk) {
      const int nb = (cur ^ 1) * 4096;             // OTHER buffer base, in shorts
      const size_t ko = (size_t)(kt + 1) * 32;
      gl_lds16(&A[ga0 + ko], &As3[nb + d0]);
      gl_lds16(&A[ga1 + ko], &As3[nb + d1]);
      gl_lds16(&B[gb0 + ko], &Bs3[nb + d0]);
      gl_lds16(&B[gb1 + ko], &Bs3[nb + d1]);
    }
    const unsigned short* Ac = As + cur * 4096;
    const unsigned short* Bc = Bs + cur * 4096;
    bf16x8 af[4], bfr[4];
#pragma unroll
    for (int i = 0; i < 4; i++) {
      int ra = wm * 64 + i * 16 + l16;
      int rb = wn * 64 + i * 16 + l16;
      af[i]  = *(const bf16x8*)&Ac[ra * 32 + (quad ^ ((ra >> 1) & 3)) * 8];
      bfr[i] = *(const bf16x8*)&Bc[rb * 32 + (quad ^ ((rb >> 1) & 3)) * 8];
    }
    __builtin_amdgcn_s_setprio(1);
#pragma unroll
    for (int i = 0; i < 4; i++)
#pragma unroll
      for (int j = 0; j < 4; j++)
        acc[i][j] = __builtin_amdgcn_mfma_f32_16x16x32_bf16(af[i], bfr[j], acc[i][j], 0, 0, 0);
    __builtin_amdgcn_s_setprio(0);
  }

#pragma unroll
  for (int i = 0; i < 4; i++) {
#pragma unroll
    for (int reg = 0; reg < 4; reg++) {
      int m = m0 + wm * 64 + i * 16 + quad * 4 + reg;
      float sm = sa[m];
#pragma unroll
      for (int j = 0; j < 4; j++) {
        int n = n0 + wn * 64 + j * 16 + l16;
        float v = acc[i][j][reg] * sm * sb[n];
        if (hasBias) v += bias[n];
        C[(size_t)m * N + n] = v;
      }
    }
  }
}

// ---------- RoPE + Hadamard-128 (q,k) and plain split (v); outputs hi/lo bf16 ----------
__global__ __launch_bounds__(256) void rope_had_kernel(const int* __restrict__ pos,
                                                       const float* __restrict__ qkv,
                                                       unsigned short* __restrict__ QH, unsigned short* __restrict__ QL,
                                                       unsigned short* __restrict__ KH, unsigned short* __restrict__ KL,
                                                       unsigned short* __restrict__ VH, unsigned short* __restrict__ VL) {
  const int w = threadIdx.x >> 6, lane = threadIdx.x & 63;
  const int vec = blockIdx.x * 4 + w;   // wave-uniform branch below
  int t, h; const float* src; unsigned short *dH, *dL; size_t o; bool doRot;
  if (vec < T_SEQ * NQ_HEADS) {
    t = vec >> 5; h = vec & 31;
    src = qkv + (size_t)t * QKV_N + h * HEAD_DIM;
    dH = QH; dL = QL; o = ((size_t)t * NQ_HEADS + h) * HEAD_DIM; doRot = true;
  } else if (vec < T_SEQ * (NQ_HEADS + NKV_HEADS)) {
    int i2 = vec - T_SEQ * NQ_HEADS; t = i2 >> 3; h = i2 & 7;
    src = qkv + (size_t)t * QKV_N + 4096 + h * HEAD_DIM;
    dH = KH; dL = KL; o = ((size_t)t * NKV_HEADS + h) * HEAD_DIM; doRot = true;
  } else {
    int i2 = vec - T_SEQ * (NQ_HEADS + NKV_HEADS); t = i2 >> 3; h = i2 & 7;
    src = qkv + (size_t)t * QKV_N + 5120 + h * HEAD_DIM;
    dH = VH; dL = VL; o = ((size_t)t * NKV_HEADS + h) * HEAD_DIM; doRot = false;
  }
  float a = src[lane], b = src[lane + 64];
  if (doRot) {
    float p = (float)pos[t];
    float fr = exp2f(-0.207620506f * (float)lane);   // 10000^-(lane/64)
    float ang = p * fr;
    float cs = cosf(ang), sn = sinf(ang);
    float na = a * cs - b * sn;
    float nb = b * cs + a * sn;
    a = na + nb; b = na - nb;
#pragma unroll
    for (int mm = 1; mm <= 32; mm <<= 1) {
      float pa = __shfl_xor(a, mm, 64);
      float pb = __shfl_xor(b, mm, 64);
      bool hi = (lane & mm) != 0;
      a = hi ? (pa - a) : (a + pa);
      b = hi ? (pb - b) : (b + pb);
    }
    a *= SCALE_H128; b *= SCALE_H128;
  }
  unsigned short ah = f2bf(a), bh = f2bf(b);
  dH[o + lane] = ah;       dH[o + lane + 64] = bh;
  dL[o + lane] = f2bf(a - bf2f(ah));
  dL[o + lane + 64] = f2bf(b - bf2f(bh));
}

// ---------- V transpose: [t][hk][128] hi/lo -> V^T [hk][128][2048] hi/lo ----------
__global__ __launch_bounds__(256) void vtrans_kernel(const unsigned short* __restrict__ Vh,
                                                     const unsigned short* __restrict__ Vl,
                                                     unsigned short* __restrict__ VtH,
                                                     unsigned short* __restrict__ VtL) {
  __shared__ unsigned short sm[17408];  // 2 x 64x136
  unsigned short* SH = sm;
  unsigned short* SL = sm + 8704;
  const int tid = threadIdx.x;
  const int t0 = blockIdx.x * 64, h = blockIdx.y;
#pragma unroll
  for (int r = 0; r < 4; r++) {
    int G = tid + r * 256;             // 1024 granules of 8 shorts
    int row = G >> 4, g = G & 15;
    size_t src = ((size_t)(t0 + row) * NKV_HEADS + h) * HEAD_DIM + g * 8;
    *(u16x8*)&SH[row * 136 + g * 8] = *(const u16x8*)&Vh[src];
    *(u16x8*)&SL[row * 136 + g * 8] = *(const u16x8*)&Vl[src];
  }
  __syncthreads();
#pragma unroll
  for (int r = 0; r < 4; r++) {
    int G = tid + r * 256;
    int d = G >> 3, gt = G & 7;
    u16x8 a, b;
#pragma unroll
    for (int e = 0; e < 8; e++) {
      a[e] = SH[(gt * 8 + e) * 136 + d];
      b[e] = SL[(gt * 8 + e) * 136 + d];
    }
    size_t dst = ((size_t)h * HEAD_DIM + d) * T_SEQ + t0 + gt * 8;
    *(u16x8*)&VtH[dst] = a;
    *(u16x8*)&VtL[dst] = b;
  }
}

// ---------- flash attention v8: v7 core + restored 8 waves/CU ------------------------
// 512 blocks x 256 threads = 2 blocks/CU (64 KB LDS each), 8 waves/CU. The former
// sequential qt-pair (phase loop) is split across the two co-resident blocks:
// block b runs qt=u, block b+256 runs qt=31-u. Under round-robin dispatch (the same
// property behind hk=b&7 XCD locality, validated by FETCH 74.8->24.6 MB), b and b+256
// land on the same CU -> per-CU tile sum = 66, flat makespan, and two INDEPENDENT
// blocks overlap each other's barrier/softmax stalls (the TLP v7 lost by running
// 1 block/CU). Core per-tile code identical to v7: 32x32x16 MFMA (2x FLOP per LDS
// byte), in-register P via shfl_xor(32), 1-barrier aged-prefetch pipeline.
// Layouts (HW-verified m74/m101): C/D col=lane&31, row=(reg&3)+8*(reg>>2)+4*(lane>>5);
// A: m=lane&31, k=8*(lane>>5)+i; B: n=lane&31, k=8*(lane>>5)+i.
__global__ __launch_bounds__(256, 2) void attn_kernel(const unsigned short* __restrict__ Qh, const unsigned short* __restrict__ Ql,
                                                      const unsigned short* __restrict__ Kh, const unsigned short* __restrict__ Kl,
                                                      const unsigned short* __restrict__ VtH, const unsigned short* __restrict__ VtL,
                                                      float* __restrict__ O) {
  __shared__ unsigned short smem[32768];   // 65536 B
  // K buf c: [c*8192, +4096) = KH, +4096 = KL        (phys g16 = log ^ (key&7))
  // V buf c: 16384 + c*8192: VH, +4096 = VL          (phys g4  = log ^ ((d>>1)&3))
  const int tid = threadIdx.x, lane = tid & 63, w = tid >> 6;
  const int l32 = lane & 31, hh = lane >> 5;   // half-select within wave

  const int b = blockIdx.x;
  const int hk = b & 7;                  // round-robin dispatch: XCD x owns kv-head x
  const int g = (b >> 3) & 31;           // 0..31
  const int hp = g & 1;                  // head pair within kv-group
  const int u = g >> 1;                  // 0..15
  const int qt = (b >> 8) ? (31 - u) : u;  // paired blocks b, b+256 -> same CU
  const int head = hk * 4 + hp * 2 + (w >> 1);
  const int qh = w & 1;                  // q 32-row half within the 64-row tile

  // staging granule geometry (256 threads, 2 granules per matrix-half per thread)
  const int kr0 = tid >> 4,         kg0 = (tid & 15) ^ (kr0 & 7);
  const int kr1 = 16 + (tid >> 4),  kg1 = (tid & 15) ^ (kr1 & 7);
  const size_t ko0 = ((size_t)kr0 * NKV_HEADS + hk) * HEAD_DIM + kg0 * 8;
  const size_t ko1 = ((size_t)kr1 * NKV_HEADS + hk) * HEAD_DIM + kg1 * 8;
  const int vd0 = tid >> 2,         vg0 = (tid & 3) ^ ((vd0 >> 1) & 3);
  const int vd1 = 64 + (tid >> 2),  vg1 = (tid & 3) ^ ((vd1 >> 1) & 3);
  const size_t vo0 = ((size_t)hk * HEAD_DIM + vd0) * T_SEQ + vg0 * 8;
  const size_t vo1 = ((size_t)hk * HEAD_DIM + vd1) * T_SEQ + vg1 * 8;
  const size_t kTile = (size_t)32 * NKV_HEADS * HEAD_DIM;

  const int q0 = qt * 64;
  const int qcol = q0 + qh * 32 + l32;     // this lane's q (softmax/O column)
  const int wqmax = q0 + qh * 32 + 31;
  const int nkt = 2 * qt + 2;

  // Q fragments (B-operand of S^T): n = q = l32, k = s*16 + 8*hh + i (contiguous 8)
  bf16x8 qbh[8], qbl[8];
#pragma unroll
  for (int s = 0; s < 8; s++) {
    size_t gq = ((size_t)qcol * NQ_HEADS + head) * HEAD_DIM + s * 16 + 8 * hh;
    qbh[s] = *(const bf16x8*)&Qh[gq];
    qbl[s] = *(const bf16x8*)&Ql[gq];
  }
  f32x16 oacc[4] = {};
  float mrow = -__builtin_inff();
  float lrow = 0.f;

  // cold start: stage tile 0 into buf 0 (once per block)
  gl_lds16(&Kh[ko0],  (lds_u16*)&smem[w * 512]);
  gl_lds16(&Kh[ko1],  (lds_u16*)&smem[2048 + w * 512]);
  gl_lds16(&Kl[ko0],  (lds_u16*)&smem[4096 + w * 512]);
  gl_lds16(&Kl[ko1],  (lds_u16*)&smem[6144 + w * 512]);
  gl_lds16(&VtH[vo0], (lds_u16*)&smem[16384 + w * 512]);
  gl_lds16(&VtH[vo1], (lds_u16*)&smem[16384 + 2048 + w * 512]);
  gl_lds16(&VtL[vo0], (lds_u16*)&smem[16384 + 4096 + w * 512]);
  gl_lds16(&VtL[vo1], (lds_u16*)&smem[16384 + 6144 + w * 512]);

#pragma unroll 1
  for (int kt = 0; kt < nkt; kt++) {
    const int cur = kt & 1;
    const unsigned short* KcH = smem + cur * 8192;
    const unsigned short* KcL = KcH + 4096;
    const unsigned short* VcH = smem + 16384 + cur * 8192;
    const unsigned short* VcL = VcH + 4096;
    // ---- the one barrier: own prefetch (aged a full iteration) drained, then
    // rendezvous -> tile kt resident in LDS for all waves; prev buffer free ----
    asm volatile("s_waitcnt vmcnt(0)" ::: "memory");
    __builtin_amdgcn_s_barrier();
    if (kt + 1 < nkt) {
      const int nb = (cur ^ 1);
      unsigned short* KB = smem + nb * 8192;
      unsigned short* VB = smem + 16384 + nb * 8192;
      size_t kOff = (size_t)(kt + 1) * kTile;
      size_t vOff = (size_t)(kt + 1) * 32;
      gl_lds16(&Kh[kOff + ko0],  (lds_u16*)&KB[w * 512]);
      gl_lds16(&Kh[kOff + ko1],  (lds_u16*)&KB[2048 + w * 512]);
      gl_lds16(&Kl[kOff + ko0],  (lds_u16*)&KB[4096 + w * 512]);
      gl_lds16(&Kl[kOff + ko1],  (lds_u16*)&KB[6144 + w * 512]);
      gl_lds16(&VtH[vOff + vo0], (lds_u16*)&VB[w * 512]);
      gl_lds16(&VtH[vOff + vo1], (lds_u16*)&VB[2048 + w * 512]);
      gl_lds16(&VtL[vOff + vo0], (lds_u16*)&VB[4096 + w * 512]);
      gl_lds16(&VtL[vOff + vo1], (lds_u16*)&VB[6144 + w * 512]);
    }
    const bool active = (kt * 32 <= wqmax);   // wave-uniform
    if (!active) continue;

    // S^T = K . Q^T  (A=K: m=key=l32, k=s*16+8*hh+i; D col=q=l32, row=key)
    f32x16 sc = {};
    __builtin_amdgcn_s_setprio(1);
#pragma unroll
    for (int s = 0; s < 8; s++) {
      int phys = (s * 2 + hh) ^ (l32 & 7);
      bf16x8 kah = *(const bf16x8*)&KcH[l32 * 128 + phys * 8];
      bf16x8 kal = *(const bf16x8*)&KcL[l32 * 128 + phys * 8];
      sc = __builtin_amdgcn_mfma_f32_32x32x16_bf16(kah, qbh[s], sc, 0, 0, 0);
      sc = __builtin_amdgcn_mfma_f32_32x32x16_bf16(kah, qbl[s], sc, 0, 0, 0);
      sc = __builtin_amdgcn_mfma_f32_32x32x16_bf16(kal, qbh[s], sc, 0, 0, 0);
    }
    __builtin_amdgcn_s_setprio(0);

    // causal mask (diagonal tiles only; wave-uniform test). key(reg) layout above.
    if (kt * 32 + 31 > q0 + qh * 32) {
#pragma unroll
      for (int r = 0; r < 16; r++) {
        int kg = kt * 32 + (r & 3) + 8 * (r >> 2) + 4 * hh;
        if (kg > qcol) sc[r] = -__builtin_inff();
      }
    }

    // online softmax in RAW score domain; lane owns one q col (16 keys; partner
    // half holds the other 16 -> one shfl_xor(32) completes the reduce)
    float tmax = sc[0];
#pragma unroll
    for (int r = 1; r < 16; r++) tmax = fmaxf(tmax, sc[r]);
    tmax = fmaxf(tmax, __shfl_xor(tmax, 32, 64));
    // defer-max (T13): skip O/l rescale while growth <= 4 in scaled domain
    if (!__all(tmax <= mrow + 45.2548f)) {
      float mnew = fmaxf(mrow, tmax);
      float alpha = __expf((mrow - mnew) * SCALE_QK);
      mrow = mnew;
      lrow *= alpha;
#pragma unroll
      for (int db = 0; db < 4; db++) oacc[db] *= alpha;
    }
    float negm = -mrow * SCALE_QK;
    float rs = 0.f;
#pragma unroll
    for (int r = 0; r < 16; r++) {
      float p = __expf(__builtin_fmaf(sc[r], SCALE_QK, negm));
      sc[r] = p;
      rs += p;
    }
    rs += __shfl_xor(rs, 32, 64);
    lrow += rs;

    // P -> bf16 hi/lo packs, in-register cross-half exchange (no LDS).
    // pair j holds keys: j0:(0,1) j1:(2,3) j2:(8,9) j3:(10,11) j4:(16,17)
    // j5:(18,19) j6:(24,25) j7:(26,27), each +4*hh.
    unsigned hi[8], lo[8];
#pragma unroll
    for (int j = 0; j < 8; j++) {
      float pa = sc[2 * j], pb = sc[2 * j + 1];
      unsigned short ha = f2bf_trunc(pa);
      unsigned short hb = f2bf_trunc(pb);
      unsigned short la = f2bf_trunc(pa - bf2f(ha));
      unsigned short lb = f2bf_trunc(pb - bf2f(hb));
      hi[j] = (unsigned)ha | ((unsigned)hb << 16);
      lo[j] = (unsigned)la | ((unsigned)lb << 16);
    }
    unsigned xh[8], xl[8];
#pragma unroll
    for (int j = 0; j < 8; j++) {
      xh[j] = __shfl_xor(hi[j], 32, 64);
      xl[j] = __shfl_xor(lo[j], 32, 64);
    }
    // B-frag step s needs keys s*16 + 8*hh .. +7  (n = q = l32 matches C col)
    union U4 { unsigned u[4]; bf16x8 v; };
    U4 fh[2], fl[2];
#pragma unroll
    for (int s = 0; s < 2; s++) {
      int b0 = s * 4;
      fh[s].u[0] = hh ? xh[b0 + 2] : hi[b0 + 0];
      fh[s].u[1] = hh ? xh[b0 + 3] : hi[b0 + 1];
      fh[s].u[2] = hh ? hi[b0 + 2] : xh[b0 + 0];
      fh[s].u[3] = hh ? hi[b0 + 3] : xh[b0 + 1];
      fl[s].u[0] = hh ? xl[b0 + 2] : lo[b0 + 0];
      fl[s].u[1] = hh ? xl[b0 + 3] : lo[b0 + 1];
      fl[s].u[2] = hh ? lo[b0 + 2] : xl[b0 + 0];
      fl[s].u[3] = hh ? lo[b0 + 3] : xl[b0 + 1];
    }

    // O^T += V^T . P  (A=V^T: m=d=db*32+l32, k=keys s*16+8*hh+i; D col=q, row=d)
    __builtin_amdgcn_s_setprio(1);
#pragma unroll
    for (int db = 0; db < 4; db++) {
      int d = db * 32 + l32;
#pragma unroll
      for (int s = 0; s < 2; s++) {
        int phys = (s * 2 + hh) ^ ((d >> 1) & 3);
        bf16x8 vah = *(const bf16x8*)&VcH[d * 32 + phys * 8];
        bf16x8 val = *(const bf16x8*)&VcL[d * 32 + phys * 8];
        oacc[db] = __builtin_amdgcn_mfma_f32_32x32x16_bf16(vah, fh[s].v, oacc[db], 0, 0, 0);
        oacc[db] = __builtin_amdgcn_mfma_f32_32x32x16_bf16(vah, fl[s].v, oacc[db], 0, 0, 0);
        oacc[db] = __builtin_amdgcn_mfma_f32_32x32x16_bf16(val, fh[s].v, oacc[db], 0, 0, 0);
      }
    }
    __builtin_amdgcn_s_setprio(0);
  }

  // epilogue: per-lane normalize; f32x4 stores.
  // reg 4g+j of oacc[db] -> d = db*32 + 8*g + 4*hh + j (j=0..3 contiguous)
  float inv = 1.0f / lrow;
#pragma unroll
  for (int db = 0; db < 4; db++) {
#pragma unroll
    for (int gg = 0; gg < 4; gg++) {
      f32x4 o;
      o[0] = oacc[db][4 * gg + 0] * inv;
      o[1] = oacc[db][4 * gg + 1] * inv;
      o[2] = oacc[db][4 * gg + 2] * inv;
      o[3] = oacc[db][4 * gg + 3] * inv;
      *(f32x4*)&O[((size_t)qcol * NQ_HEADS + head) * HEAD_DIM + db * 32 + 8 * gg + 4 * hh] = o;
    }
  }
}

// ---------- head-Hadamard (32) + per-token int4 fake-quant ----------
__global__ __launch_bounds__(128) void headhad_quant(const float* __restrict__ attn,
                                                     unsigned short* __restrict__ Aq,
                                                     float* __restrict__ Sa) {
  const int t = blockIdx.x, d = threadIdx.x; // 128 threads, one d-column each
  float x[32];
#pragma unroll
  for (int h = 0; h < 32; h++) x[h] = attn[(size_t)t * 4096 + h * 128 + d];
#pragma unroll
  for (int s = 1; s < 32; s <<= 1) {
#pragma unroll
    for (int i = 0; i < 32; i++) {
      if (!(i & s)) {
        float u = x[i], v = x[i | s];
        x[i] = u + v; x[i | s] = u - v;
      }
    }
  }
  float amax = 0.f;
#pragma unroll
  for (int h = 0; h < 32; h++) { x[h] *= SCALE_H32; amax = fmaxf(amax, fabsf(x[h])); }
#pragma unroll
  for (int mm = 1; mm < 64; mm <<= 1) amax = fmaxf(amax, __shfl_xor(amax, mm, 64));
  __shared__ float red[2];
  if ((threadIdx.x & 63) == 0) red[threadIdx.x >> 6] = amax;
  __syncthreads();
  amax = fmaxf(red[0], red[1]);
  float s = fmaxf(amax / 7.0f, 1e-8f);
#pragma unroll
  for (int h = 0; h < 32; h++) {
    float q = rintf(x[h] / s);
    q = fminf(fmaxf(q, -8.f), 7.f);
    Aq[(size_t)t * 4096 + h * 128 + d] = f2bf(q);
  }
  if (threadIdx.x == 0) Sa[t] = s;
}

// ---------- launch ----------
extern "C" void kernel_launch(void* const* d_in, const int* in_sizes, int n_in,
                              void* d_out, int out_size, void* d_ws, size_t ws_size,
                              hipStream_t stream) {
  const int*   positions = (const int*)d_in[0];
  const float* hidden    = (const float*)d_in[1];
  const float* qkv_w     = (const float*)d_in[2];
  const float* qkv_b     = (const float*)d_in[3];
  const float* o_w       = (const float*)d_in[4];
  float* out = (float*)d_out;
  char* ws = (char*)d_ws;

  // region map (total ~160.1 MB)
  unsigned short* wq   = (unsigned short*)(ws + 0);          // 6144x4096 bf16 ; later owq 4096x4096
  unsigned short* xq   = (unsigned short*)(ws + 50331648);   // 2048x4096 bf16 ; later vth/vtl then aq
  float*          qkv  = (float*)(ws + 67108864);            // 2048x6144 f32 ; later attn f32
  unsigned short* qh   = (unsigned short*)(ws + 117440512);  // 2048x32x128
  unsigned short* ql   = (unsigned short*)(ws + 134217728);
  unsigned short* kh   = (unsigned short*)(ws + 150994944);  // 2048x8x128
  unsigned short* kl   = (unsigned short*)(ws + 155189248);
  unsigned short* vh   = (unsigned short*)(ws + 159383552);
  unsigned short* vl   = (unsigned short*)(ws + 163577856);
  float* s_x  = (float*)(ws + 167772160);
  float* s_w  = (float*)(ws + 167780352);
  float* s_a  = (float*)(ws + 167804928);
  float* s_ow = (float*)(ws + 167813120);
  unsigned short* owq  = wq;                                 // reuse R0 after GEMM1
  unsigned short* aq   = xq;                                 // reuse R1 after attn
  unsigned short* vth  = (unsigned short*)(ws + 50331648);   // inside R1 (xq dead after GEMM1)
  unsigned short* vtl  = (unsigned short*)(ws + 54525952);
  float* attnbuf       = qkv;                                // reuse R2 after rope

  // 1. quantize activations + qkv weights (single-pass)
  quant_rows<<<T_SEQ, 256, 0, stream>>>(hidden, xq, s_x, HIDDEN);
  quant_rows<<<QKV_N, 256, 0, stream>>>(qkv_w, wq, s_w, HIDDEN);
  // 2. QKV GEMM (exact int4 dot in bf16 MFMA), pipelined staging
  gemm_q4<<<dim3(QKV_N / 128, T_SEQ / 128), 256, 0, stream>>>(xq, wq, s_x, s_w, qkv_b,
                                                              qkv, T_SEQ, QKV_N, HIDDEN, 1);
  // 3. RoPE + Hadamard-128, hi/lo split outputs
  rope_had_kernel<<<(T_SEQ * 48) / 4, 256, 0, stream>>>(positions, qkv, qh, ql, kh, kl, vh, vl);
  // 3b. V transpose into [hk][d][t] (R1 is free now)
  vtrans_kernel<<<dim3(T_SEQ / 64, NKV_HEADS), 256, 0, stream>>>(vh, vl, vth, vtl);
  // 4. quantize o_w (into reused R0)
  quant_rows<<<HIDDEN, 256, 0, stream>>>(o_w, owq, s_ow, HIDDEN);
  // 5. attention v8: 32x32 MFMA, in-reg P, 512 blocks = 2 blocks/CU (paired qt)
  attn_kernel<<<dim3(512), 256, 0, stream>>>(qh, ql, kh, kl, vth, vtl, attnbuf);
  // 6. head-Hadamard + per-token fake-quant (into reused R1; vth/vtl dead)
  headhad_quant<<<T_SEQ, 128, 0, stream>>>(attnbuf, aq, s_a);
  // 7. O-proj GEMM, pipelined staging
  gemm_q4<<<dim3(HIDDEN / 128, T_SEQ / 128), 256, 0, stream>>>(aq, owq, s_a, s_ow, nullptr,
                                                               out, T_SEQ, HIDDEN, HIDDEN, 0);
}